// Round 1
// baseline (1240.648 us; speedup 1.0000x reference)
//
#include <hip/hip_runtime.h>

#define SS 256
#define BB 512
#define DIN 512
#define DH 1024
#define GG 1536  // DIN + DH

// ---------------------------------------------------------------------------
// K1: fold Mall[d][k][p] = sum_h W_lin[k][d][h] * W_g0[k][h][p]
//     d in [0, G): d<DIN rows feed the x-projection, d>=DIN rows feed u.
//     One wave per (k, d). Layout: Mall[d*16 + k*4 + p].
// ---------------------------------------------------------------------------
__global__ void __launch_bounds__(256) fold_kernel(
    const float* __restrict__ W_lin,   // [4][G][DH]
    const float* __restrict__ W_g0,    // [4][DH][4]
    float* __restrict__ Mall)          // [G][16]
{
    int wid  = (blockIdx.x * blockDim.x + threadIdx.x) >> 6;
    int lane = threadIdx.x & 63;
    int d = wid % GG;
    int k = wid / GG;
    if (k >= 4) return;

    const float* wrow = W_lin + ((size_t)k * GG + d) * DH;
    const float* g0   = W_g0 + (size_t)k * DH * 4;

    float a0 = 0.f, a1 = 0.f, a2 = 0.f, a3 = 0.f;
#pragma unroll
    for (int j = 0; j < DH / 64; ++j) {
        int h = lane + j * 64;
        float w = wrow[h];
        float4 gv = *reinterpret_cast<const float4*>(g0 + (size_t)h * 4);
        a0 = fmaf(w, gv.x, a0);
        a1 = fmaf(w, gv.y, a1);
        a2 = fmaf(w, gv.z, a2);
        a3 = fmaf(w, gv.w, a3);
    }
#pragma unroll
    for (int off = 32; off >= 1; off >>= 1) {
        a0 += __shfl_xor(a0, off);
        a1 += __shfl_xor(a1, off);
        a2 += __shfl_xor(a2, off);
        a3 += __shfl_xor(a3, off);
    }
    if (lane == 0) {
        float4 r = make_float4(a0, a1, a2, a3);
        *reinterpret_cast<float4*>(Mall + (size_t)(d * 16 + k * 4)) = r;
    }
}

// ---------------------------------------------------------------------------
// K2: u[kp] = sum_{d=DIN}^{G-1} Mall[d][kp]   (the h-part rowsum fold)
//     v[kp] = b_g0[kp] + sum_h b_lin[k][h] * W_g0[k][h][p]
// ---------------------------------------------------------------------------
__global__ void uv_kernel(
    const float* __restrict__ Mall,
    const float* __restrict__ b_lin,   // [4][DH]
    const float* __restrict__ W_g0,    // [4][DH][4]
    const float* __restrict__ b_g0,    // [4][4]
    float* __restrict__ uv)            // u[16], v[16]
{
    int t = threadIdx.x;
    if (t < 16) {
        float s = 0.f;
        for (int d = DIN; d < GG; ++d) s += Mall[(size_t)d * 16 + t];
        uv[t] = s;
    } else if (t < 32) {
        int kp = t - 16;
        int k = kp >> 2, p = kp & 3;
        float s = b_g0[k * 4 + p];
        for (int h = 0; h < DH; ++h)
            s = fmaf(b_lin[(size_t)k * DH + h], W_g0[((size_t)k * DH + h) * 4 + p], s);
        uv[16 + kp] = s;
    }
}

// ---------------------------------------------------------------------------
// K3: A[row][kp] = sum_{d<DIN} x[row][d] * Mall[d][kp],  row = t*B + b.
//     128 threads/block, 4 rows/thread -> 512 rows/block, 256 blocks (1/CU).
//     M reads are wave-uniform -> compiler scalarizes to s_load (K$).
// ---------------------------------------------------------------------------
__global__ void __launch_bounds__(128) proj_kernel(
    const float* __restrict__ x,       // [S*B][DIN]
    const float* __restrict__ Mall,    // [G][16] (only d<DIN used)
    float* __restrict__ A)             // [S*B][16]
{
    const int tid = threadIdx.x;
    const size_t base = (size_t)blockIdx.x * 512 + tid;
    const float4* __restrict__ x4 = reinterpret_cast<const float4*>(x);
    const float4* __restrict__ M4 = reinterpret_cast<const float4*>(Mall);

    float acc[4][16];
#pragma unroll
    for (int r = 0; r < 4; ++r)
#pragma unroll
        for (int j = 0; j < 16; ++j) acc[r][j] = 0.f;

    for (int d4 = 0; d4 < DIN / 4; ++d4) {
        float4 xv[4];
#pragma unroll
        for (int r = 0; r < 4; ++r)
            xv[r] = x4[(base + (size_t)r * 128) * (DIN / 4) + d4];
#pragma unroll
        for (int dd = 0; dd < 4; ++dd) {
            const int d = d4 * 4 + dd;
            float4 m0 = M4[d * 4 + 0];
            float4 m1 = M4[d * 4 + 1];
            float4 m2 = M4[d * 4 + 2];
            float4 m3 = M4[d * 4 + 3];
#pragma unroll
            for (int r = 0; r < 4; ++r) {
                float xs = (dd == 0) ? xv[r].x : (dd == 1) ? xv[r].y
                           : (dd == 2) ? xv[r].z : xv[r].w;
                acc[r][0]  = fmaf(xs, m0.x, acc[r][0]);
                acc[r][1]  = fmaf(xs, m0.y, acc[r][1]);
                acc[r][2]  = fmaf(xs, m0.z, acc[r][2]);
                acc[r][3]  = fmaf(xs, m0.w, acc[r][3]);
                acc[r][4]  = fmaf(xs, m1.x, acc[r][4]);
                acc[r][5]  = fmaf(xs, m1.y, acc[r][5]);
                acc[r][6]  = fmaf(xs, m1.z, acc[r][6]);
                acc[r][7]  = fmaf(xs, m1.w, acc[r][7]);
                acc[r][8]  = fmaf(xs, m2.x, acc[r][8]);
                acc[r][9]  = fmaf(xs, m2.y, acc[r][9]);
                acc[r][10] = fmaf(xs, m2.z, acc[r][10]);
                acc[r][11] = fmaf(xs, m2.w, acc[r][11]);
                acc[r][12] = fmaf(xs, m3.x, acc[r][12]);
                acc[r][13] = fmaf(xs, m3.y, acc[r][13]);
                acc[r][14] = fmaf(xs, m3.z, acc[r][14]);
                acc[r][15] = fmaf(xs, m3.w, acc[r][15]);
            }
        }
    }
#pragma unroll
    for (int r = 0; r < 4; ++r) {
        size_t row = base + (size_t)r * 128;
        float4* __restrict__ Ao = reinterpret_cast<float4*>(A) + row * 4;
        Ao[0] = make_float4(acc[r][0],  acc[r][1],  acc[r][2],  acc[r][3]);
        Ao[1] = make_float4(acc[r][4],  acc[r][5],  acc[r][6],  acc[r][7]);
        Ao[2] = make_float4(acc[r][8],  acc[r][9],  acc[r][10], acc[r][11]);
        Ao[3] = make_float4(acc[r][12], acc[r][13], acc[r][14], acc[r][15]);
    }
}

// ---------------------------------------------------------------------------
// K4: sequential scan. One block, 512 threads, thread b owns batch element b.
//     s_{t} = o * tanh(c_t),  c_t = f*c_{t-1} + i*g,  gates from tiny MLP on
//     z0 = A[t,b,:] + s_{t-1}*u + v.  Prefetch A one step ahead.
// ---------------------------------------------------------------------------
__device__ __forceinline__ float tanh_fast(float x) {
    float ax = fabsf(x);
    float e  = __expf(-2.f * ax);          // in (0,1], no overflow
    float r  = (1.f - e) / (1.f + e);
    return copysignf(r, x);
}
__device__ __forceinline__ float sigm(float x) {
    return 1.f / (1.f + __expf(-x));
}

__global__ void __launch_bounds__(512) scan_kernel(
    const float* __restrict__ A,        // [S*B][16]
    const float* __restrict__ h0,       // [B][DH] (row-constant)
    const float* __restrict__ c0,       // [B][DH] (row-constant)
    const float* __restrict__ uv,       // u[16], v[16]
    const float* __restrict__ Wg1,      // [4][4][4]
    const float* __restrict__ bg1,      // [4][4]
    const float* __restrict__ Wg2,      // [4][4]
    const float* __restrict__ bg2,      // [4]
    float* __restrict__ s_tab,          // [S][B]
    float* __restrict__ c_fin)          // [B]
{
    const int b = threadIdx.x;

    float u[16], v[16];
#pragma unroll
    for (int j = 0; j < 16; ++j) { u[j] = uv[j]; v[j] = uv[16 + j]; }
    float w1[64];
#pragma unroll
    for (int j = 0; j < 64; ++j) w1[j] = Wg1[j];
    float B1[16];
#pragma unroll
    for (int j = 0; j < 16; ++j) B1[j] = bg1[j];
    float w2[16];
#pragma unroll
    for (int j = 0; j < 16; ++j) w2[j] = Wg2[j];
    float B2[4];
#pragma unroll
    for (int j = 0; j < 4; ++j) B2[j] = bg2[j];

    float s = h0[(size_t)b * DH];
    float c = c0[(size_t)b * DH];

    const float4* __restrict__ A4 = reinterpret_cast<const float4*>(A);
    float4 cur0 = A4[(size_t)b * 4 + 0];
    float4 cur1 = A4[(size_t)b * 4 + 1];
    float4 cur2 = A4[(size_t)b * 4 + 2];
    float4 cur3 = A4[(size_t)b * 4 + 3];

    for (int t = 0; t < SS; ++t) {
        // prefetch next step (t=SS-1 reads into the s_tab region: allocated, unused)
        size_t nb = ((size_t)(t + 1) * BB + b) * 4;
        float4 n0 = A4[nb + 0];
        float4 n1 = A4[nb + 1];
        float4 n2 = A4[nb + 2];
        float4 n3 = A4[nb + 3];

        float z0[16] = { cur0.x, cur0.y, cur0.z, cur0.w,
                         cur1.x, cur1.y, cur1.z, cur1.w,
                         cur2.x, cur2.y, cur2.z, cur2.w,
                         cur3.x, cur3.y, cur3.z, cur3.w };
#pragma unroll
        for (int j = 0; j < 16; ++j) z0[j] = fmaf(s, u[j], z0[j]) + v[j];

        float z2[4];
#pragma unroll
        for (int k = 0; k < 4; ++k) {
            float zz = B2[k];
#pragma unroll
            for (int q = 0; q < 4; ++q) {
                float t1 = B1[k * 4 + q];
#pragma unroll
                for (int p = 0; p < 4; ++p)
                    t1 = fmaf(z0[k * 4 + p], w1[(k * 4 + p) * 4 + q], t1);
                t1 = fmaxf(t1, 0.f);
                zz = fmaf(t1, w2[k * 4 + q], zz);
            }
            z2[k] = tanh_fast(zz);
        }
        float fg = sigm(z2[0]);
        float ig = sigm(z2[1]);
        float gg = tanh_fast(z2[2]);
        float og = sigm(z2[3]);
        c = fmaf(fg, c, ig * gg);
        s = og * tanh_fast(c);
        s_tab[(size_t)t * BB + b] = s;

        cur0 = n0; cur1 = n1; cur2 = n2; cur3 = n3;
    }
    c_fin[b] = c;
}

// ---------------------------------------------------------------------------
// K5: broadcast write. outs[t][b][h] = s_tab[t][b]; hx[b][h] = s_tab[S-1][b];
//     cx[b][h] = c_fin[b]. Pure fill, float4 stores, grid-stride.
// ---------------------------------------------------------------------------
__global__ void __launch_bounds__(256) writeout_kernel(
    const float* __restrict__ s_tab,
    const float* __restrict__ c_fin,
    float4* __restrict__ out)
{
    const size_t OUTS4 = (size_t)SS * BB * (DH / 4);   // 33,554,432
    const size_t HX4   = (size_t)BB * (DH / 4);        // 131,072
    const size_t TOT4  = OUTS4 + 2 * HX4;
    size_t stride = (size_t)gridDim.x * blockDim.x;
    for (size_t i = (size_t)blockIdx.x * blockDim.x + threadIdx.x;
         i < TOT4; i += stride) {
        float val;
        if (i < OUTS4) {
            val = s_tab[i >> 8];                         // (t*B+b)
        } else if (i < OUTS4 + HX4) {
            val = s_tab[(size_t)(SS - 1) * BB + ((i - OUTS4) >> 8)];
        } else {
            val = c_fin[(i - OUTS4 - HX4) >> 8];
        }
        out[i] = make_float4(val, val, val, val);
    }
}

// ---------------------------------------------------------------------------
extern "C" void kernel_launch(void* const* d_in, const int* in_sizes, int n_in,
                              void* d_out, int out_size, void* d_ws, size_t ws_size,
                              hipStream_t stream) {
    const float* x     = (const float*)d_in[0];
    const float* h0    = (const float*)d_in[1];
    const float* c0    = (const float*)d_in[2];
    const float* W_lin = (const float*)d_in[3];
    const float* b_lin = (const float*)d_in[4];
    const float* W_g0  = (const float*)d_in[5];
    const float* b_g0  = (const float*)d_in[6];
    const float* W_g1  = (const float*)d_in[7];
    const float* b_g1  = (const float*)d_in[8];
    const float* W_g2  = (const float*)d_in[9];
    const float* b_g2  = (const float*)d_in[10];

    char* ws = (char*)d_ws;
    float* Mall  = (float*)(ws);                                   // 98,304 B
    float* uv    = (float*)(ws + 98304);                           // 128 B
    float* A     = (float*)(ws + 131072);                          // 8,388,608 B
    float* s_tab = (float*)(ws + 131072 + 8388608);                // 524,288 B
    float* c_fin = (float*)(ws + 131072 + 8388608 + 524288);       // 2,048 B

    // K1: fold M = W_lin(.,d,.) @ W_g0 for all G rows. 4*G waves.
    fold_kernel<<<(4 * GG) / 4, 256, 0, stream>>>(W_lin, W_g0, Mall);
    // K2: u, v constants.
    uv_kernel<<<1, 64, 0, stream>>>(Mall, b_lin, W_g0, b_g0, uv);
    // K3: A = x @ M  (memory-bound on the 256 MB x read).
    proj_kernel<<<256, 128, 0, stream>>>(x, Mall, A);
    // K4: sequential 256-step scan, 512 lanes.
    scan_kernel<<<1, 512, 0, stream>>>(A, h0, c0, uv, W_g1, b_g1, W_g2, b_g2,
                                       s_tab, c_fin);
    // K5: broadcast-fill the 541 MB output.
    writeout_kernel<<<2048, 256, 0, stream>>>(s_tab, c_fin, (float4*)d_out);
}

// Round 2
// 943.119 us; speedup vs baseline: 1.3155x; 1.3155x over previous
//
#include <hip/hip_runtime.h>

#define SS 256
#define BB 512
#define DIN 512
#define DH 1024
#define GG 1536  // DIN + DH
#define PD 8     // scan prefetch depth

typedef float f32x4 __attribute__((ext_vector_type(4)));

// ---------------------------------------------------------------------------
// K1: fold Mall[d][k][p] = sum_h W_lin[k][d][h] * W_g0[k][h][p]
//     One wave per (k, d). Layout: Mall[d*16 + k*4 + p].
// ---------------------------------------------------------------------------
__global__ void __launch_bounds__(256) fold_kernel(
    const float* __restrict__ W_lin,   // [4][G][DH]
    const float* __restrict__ W_g0,    // [4][DH][4]
    float* __restrict__ Mall)          // [G][16]
{
    int wid  = (blockIdx.x * blockDim.x + threadIdx.x) >> 6;
    int lane = threadIdx.x & 63;
    int d = wid % GG;
    int k = wid / GG;
    if (k >= 4) return;

    const float* wrow = W_lin + ((size_t)k * GG + d) * DH;
    const float* g0   = W_g0 + (size_t)k * DH * 4;

    float a0 = 0.f, a1 = 0.f, a2 = 0.f, a3 = 0.f;
#pragma unroll
    for (int j = 0; j < DH / 64; ++j) {
        int h = lane + j * 64;
        float w = wrow[h];
        float4 gv = *reinterpret_cast<const float4*>(g0 + (size_t)h * 4);
        a0 = fmaf(w, gv.x, a0);
        a1 = fmaf(w, gv.y, a1);
        a2 = fmaf(w, gv.z, a2);
        a3 = fmaf(w, gv.w, a3);
    }
#pragma unroll
    for (int off = 32; off >= 1; off >>= 1) {
        a0 += __shfl_xor(a0, off);
        a1 += __shfl_xor(a1, off);
        a2 += __shfl_xor(a2, off);
        a3 += __shfl_xor(a3, off);
    }
    if (lane == 0) {
        *reinterpret_cast<float4*>(Mall + (size_t)(d * 16 + k * 4)) =
            make_float4(a0, a1, a2, a3);
    }
}

// ---------------------------------------------------------------------------
// K2: u[kp] = sum_{d>=DIN} Mall[d][kp];  v[kp] = b_g0[kp] + b_lin[k].W_g0[.,p]
//     1024 threads = 16 waves; wave w owns kp = w. Wave-parallel reduce.
// ---------------------------------------------------------------------------
__global__ void __launch_bounds__(1024) uv_kernel(
    const float* __restrict__ Mall,
    const float* __restrict__ b_lin,   // [4][DH]
    const float* __restrict__ W_g0,    // [4][DH][4]
    const float* __restrict__ b_g0,    // [4][4]
    float* __restrict__ uv)            // u[16], v[16]
{
    int w = threadIdx.x >> 6, lane = threadIdx.x & 63;
    int k = w >> 2, p = w & 3;

    float sv = 0.f;
#pragma unroll
    for (int j = 0; j < DH / 64; ++j) {
        int h = lane + j * 64;
        sv = fmaf(b_lin[(size_t)k * DH + h],
                  W_g0[((size_t)k * DH + h) * 4 + p], sv);
    }
    float su = 0.f;
#pragma unroll
    for (int j = 0; j < DH / 64; ++j) {
        int d = DIN + lane + j * 64;
        su += Mall[(size_t)d * 16 + w];
    }
#pragma unroll
    for (int off = 32; off >= 1; off >>= 1) {
        sv += __shfl_xor(sv, off);
        su += __shfl_xor(su, off);
    }
    if (lane == 0) {
        uv[w]      = su;
        uv[16 + w] = b_g0[k * 4 + p] + sv;
    }
}

// ---------------------------------------------------------------------------
// K3: A[row][kp] = sum_d x[row][d] * Mall[d][kp]. One row per thread,
//     512 blocks x 256 threads (8 waves/CU). 64B-chunk double-buffered loads;
//     M reads are wave-uniform -> scalarized to s_load (K$).
// ---------------------------------------------------------------------------
__global__ void __launch_bounds__(256) proj_kernel(
    const float* __restrict__ x,       // [S*B][DIN]
    const float* __restrict__ Mall,    // [G][16] (only d<DIN used)
    float* __restrict__ A)             // [S*B][16]
{
    const size_t row = (size_t)blockIdx.x * 256 + threadIdx.x;
    const float4* __restrict__ xr = reinterpret_cast<const float4*>(x) + row * (DIN / 4);
    const float4* __restrict__ M4 = reinterpret_cast<const float4*>(Mall);

    float acc[16];
#pragma unroll
    for (int j = 0; j < 16; ++j) acc[j] = 0.f;

    float4 c0 = xr[0], c1 = xr[1], c2 = xr[2], c3 = xr[3];

    for (int cc = 0; cc < DIN / 16; ++cc) {
        int nc = (cc + 1 < DIN / 16) ? cc + 1 : cc;
        float4 n0 = xr[nc * 4 + 0];
        float4 n1 = xr[nc * 4 + 1];
        float4 n2 = xr[nc * 4 + 2];
        float4 n3 = xr[nc * 4 + 3];

        float xv[16] = { c0.x, c0.y, c0.z, c0.w, c1.x, c1.y, c1.z, c1.w,
                         c2.x, c2.y, c2.z, c2.w, c3.x, c3.y, c3.z, c3.w };
#pragma unroll
        for (int dd = 0; dd < 16; ++dd) {
            int d = cc * 16 + dd;
            float4 m0 = M4[d * 4 + 0];
            float4 m1 = M4[d * 4 + 1];
            float4 m2 = M4[d * 4 + 2];
            float4 m3 = M4[d * 4 + 3];
            float xs = xv[dd];
            acc[0]  = fmaf(xs, m0.x, acc[0]);
            acc[1]  = fmaf(xs, m0.y, acc[1]);
            acc[2]  = fmaf(xs, m0.z, acc[2]);
            acc[3]  = fmaf(xs, m0.w, acc[3]);
            acc[4]  = fmaf(xs, m1.x, acc[4]);
            acc[5]  = fmaf(xs, m1.y, acc[5]);
            acc[6]  = fmaf(xs, m1.z, acc[6]);
            acc[7]  = fmaf(xs, m1.w, acc[7]);
            acc[8]  = fmaf(xs, m2.x, acc[8]);
            acc[9]  = fmaf(xs, m2.y, acc[9]);
            acc[10] = fmaf(xs, m2.z, acc[10]);
            acc[11] = fmaf(xs, m2.w, acc[11]);
            acc[12] = fmaf(xs, m3.x, acc[12]);
            acc[13] = fmaf(xs, m3.y, acc[13]);
            acc[14] = fmaf(xs, m3.z, acc[14]);
            acc[15] = fmaf(xs, m3.w, acc[15]);
        }
        c0 = n0; c1 = n1; c2 = n2; c3 = n3;
    }

    float4* __restrict__ Ao = reinterpret_cast<float4*>(A) + row * 4;
    Ao[0] = make_float4(acc[0],  acc[1],  acc[2],  acc[3]);
    Ao[1] = make_float4(acc[4],  acc[5],  acc[6],  acc[7]);
    Ao[2] = make_float4(acc[8],  acc[9],  acc[10], acc[11]);
    Ao[3] = make_float4(acc[12], acc[13], acc[14], acc[15]);
}

// ---------------------------------------------------------------------------
// K4: sequential scan. 8 blocks x 64 threads (8 CUs), thread owns batch b.
//     PD-deep register prefetch, fully unrolled (static buf indexing).
// ---------------------------------------------------------------------------
__device__ __forceinline__ float tanh_fast(float x) {
    float ax = fabsf(x);
    float e  = __expf(-2.f * ax);          // in (0,1], no overflow
    float r  = (1.f - e) / (1.f + e);
    return copysignf(r, x);
}
__device__ __forceinline__ float sigm(float x) {
    return 1.f / (1.f + __expf(-x));
}

__global__ void __launch_bounds__(64) scan_kernel(
    const float* __restrict__ A,        // [S*B][16]
    const float* __restrict__ h0,       // [B][DH] (row-constant)
    const float* __restrict__ c0,       // [B][DH] (row-constant)
    const float* __restrict__ uv,       // u[16], v[16]
    const float* __restrict__ Wg1,      // [4][4][4]
    const float* __restrict__ bg1,      // [4][4]
    const float* __restrict__ Wg2,      // [4][4]
    const float* __restrict__ bg2,      // [4]
    float* __restrict__ s_tab,          // [S][B]
    float* __restrict__ c_fin)          // [B]
{
    const int b = blockIdx.x * 64 + threadIdx.x;

    float u[16], v[16];
#pragma unroll
    for (int j = 0; j < 16; ++j) { u[j] = uv[j]; v[j] = uv[16 + j]; }
    float w1[64];
#pragma unroll
    for (int j = 0; j < 64; ++j) w1[j] = Wg1[j];
    float B1[16];
#pragma unroll
    for (int j = 0; j < 16; ++j) B1[j] = bg1[j];
    float w2[16];
#pragma unroll
    for (int j = 0; j < 16; ++j) w2[j] = Wg2[j];
    float B2[4];
#pragma unroll
    for (int j = 0; j < 4; ++j) B2[j] = bg2[j];

    float s = h0[(size_t)b * DH];
    float c = c0[(size_t)b * DH];

    const float4* __restrict__ A4 = reinterpret_cast<const float4*>(A);

    float4 buf[PD][4];
#pragma unroll
    for (int j = 0; j < PD; ++j) {
        size_t base = ((size_t)j * BB + b) * 4;
        buf[j][0] = A4[base + 0];
        buf[j][1] = A4[base + 1];
        buf[j][2] = A4[base + 2];
        buf[j][3] = A4[base + 3];
    }

    for (int to = 0; to < SS; to += PD) {
#pragma unroll
        for (int j = 0; j < PD; ++j) {
            const int t = to + j;
            float z0[16] = { buf[j][0].x, buf[j][0].y, buf[j][0].z, buf[j][0].w,
                             buf[j][1].x, buf[j][1].y, buf[j][1].z, buf[j][1].w,
                             buf[j][2].x, buf[j][2].y, buf[j][2].z, buf[j][2].w,
                             buf[j][3].x, buf[j][3].y, buf[j][3].z, buf[j][3].w };
            // issue prefetch for step t+PD immediately (PD-1 steps of slack)
            int nt = t + PD; nt = nt < SS ? nt : SS - 1;
            size_t nb = ((size_t)nt * BB + b) * 4;
            buf[j][0] = A4[nb + 0];
            buf[j][1] = A4[nb + 1];
            buf[j][2] = A4[nb + 2];
            buf[j][3] = A4[nb + 3];

#pragma unroll
            for (int q = 0; q < 16; ++q) z0[q] = fmaf(s, u[q], z0[q]) + v[q];

            float z2[4];
#pragma unroll
            for (int k = 0; k < 4; ++k) {
                float zz = B2[k];
#pragma unroll
                for (int q = 0; q < 4; ++q) {
                    float t1 = B1[k * 4 + q];
#pragma unroll
                    for (int p = 0; p < 4; ++p)
                        t1 = fmaf(z0[k * 4 + p], w1[(k * 4 + p) * 4 + q], t1);
                    t1 = fmaxf(t1, 0.f);
                    zz = fmaf(t1, w2[k * 4 + q], zz);
                }
                z2[k] = tanh_fast(zz);
            }
            float fg = sigm(z2[0]);
            float ig = sigm(z2[1]);
            float gg = tanh_fast(z2[2]);
            float og = sigm(z2[3]);
            c = fmaf(fg, c, ig * gg);
            s = og * tanh_fast(c);
            s_tab[(size_t)t * BB + b] = s;
        }
    }
    c_fin[b] = c;
}

// ---------------------------------------------------------------------------
// K5: broadcast write. outs[t][b][h] = s_tab[t][b]; hx = s_tab[S-1]; cx = c_fin.
//     Nontemporal dwordx4 stores (write-only stream).
// ---------------------------------------------------------------------------
__global__ void __launch_bounds__(256) writeout_kernel(
    const float* __restrict__ s_tab,
    const float* __restrict__ c_fin,
    f32x4* __restrict__ out)
{
    const size_t OUTS4 = (size_t)SS * BB * (DH / 4);   // 33,554,432
    const size_t HX4   = (size_t)BB * (DH / 4);        // 131,072
    const size_t TOT4  = OUTS4 + 2 * HX4;
    size_t stride = (size_t)gridDim.x * blockDim.x;
    for (size_t i = (size_t)blockIdx.x * blockDim.x + threadIdx.x;
         i < TOT4; i += stride) {
        float val;
        if (i < OUTS4) {
            val = s_tab[i >> 8];                         // (t*B+b)
        } else if (i < OUTS4 + HX4) {
            val = s_tab[(size_t)(SS - 1) * BB + ((i - OUTS4) >> 8)];
        } else {
            val = c_fin[(i - OUTS4 - HX4) >> 8];
        }
        f32x4 vv = { val, val, val, val };
        __builtin_nontemporal_store(vv, out + i);
    }
}

// ---------------------------------------------------------------------------
extern "C" void kernel_launch(void* const* d_in, const int* in_sizes, int n_in,
                              void* d_out, int out_size, void* d_ws, size_t ws_size,
                              hipStream_t stream) {
    const float* x     = (const float*)d_in[0];
    const float* h0    = (const float*)d_in[1];
    const float* c0    = (const float*)d_in[2];
    const float* W_lin = (const float*)d_in[3];
    const float* b_lin = (const float*)d_in[4];
    const float* W_g0  = (const float*)d_in[5];
    const float* b_g0  = (const float*)d_in[6];
    const float* W_g1  = (const float*)d_in[7];
    const float* b_g1  = (const float*)d_in[8];
    const float* W_g2  = (const float*)d_in[9];
    const float* b_g2  = (const float*)d_in[10];

    char* ws = (char*)d_ws;
    float* Mall  = (float*)(ws);                                   // 98,304 B
    float* uv    = (float*)(ws + 98304);                           // 128 B
    float* A     = (float*)(ws + 131072);                          // 8,388,608 B
    float* s_tab = (float*)(ws + 131072 + 8388608);                // 524,288 B
    float* c_fin = (float*)(ws + 131072 + 8388608 + 524288);       // 2,048 B

    fold_kernel<<<(4 * GG) / 4, 256, 0, stream>>>(W_lin, W_g0, Mall);
    uv_kernel<<<1, 1024, 0, stream>>>(Mall, b_lin, W_g0, b_g0, uv);
    proj_kernel<<<512, 256, 0, stream>>>(x, Mall, A);
    scan_kernel<<<BB / 64, 64, 0, stream>>>(A, h0, c0, uv, W_g1, b_g1, W_g2, b_g2,
                                            s_tab, c_fin);
    writeout_kernel<<<4096, 256, 0, stream>>>(s_tab, c_fin, (f32x4*)d_out);
}